// Round 1
// 690.880 us; speedup vs baseline: 1.2520x; 1.2520x over previous
//
#include <hip/hip_runtime.h>
#include <hip/hip_bf16.h>
#include <math.h>

#define NTOK   8192
#define HIDDEN 2048
#define FFN_   2048
#define NEXP   8
#define TOPK   2
#define MTOT   (NTOK*TOPK)   // 16384 scattered rows
#define CAP    (MTOT/NEXP)   // 2048 rows per expert
#define KD     2048          // K of both GEMMs
#define NT     32            // K-tiles of 64

typedef __bf16 bf16_t;
typedef __attribute__((ext_vector_type(8))) __bf16 bf16x8;
typedef __attribute__((ext_vector_type(4))) float  f32x4;

// async global->LDS, 16B/lane: LDS dest must be wave-uniform base + lane*16 (linear).
__device__ __forceinline__ void async16(const bf16_t* g, bf16_t* l) {
    __builtin_amdgcn_global_load_lds(
        (const __attribute__((address_space(1))) void*)g,
        (__attribute__((address_space(3))) void*)l, 16, 0, 0);
}

#define FENCE() asm volatile("" ::: "memory")
#define BAR()   do { FENCE(); __builtin_amdgcn_s_barrier(); FENCE(); } while (0)

__global__ void k_build_inv(const int* __restrict__ scat, int* __restrict__ inv) {
    int i = blockIdx.x * 256 + threadIdx.x;
    inv[scat[i]] = i;
}

// fp32 -> bf16 cast, 8 elems/thread
__global__ void k_cast(const float* __restrict__ src, bf16_t* __restrict__ dst) {
    int idx = blockIdx.x * 256 + threadIdx.x;
    const float4* p = (const float4*)(src + (size_t)idx * 8);
    float4 a = p[0], b = p[1];
    bf16x8 o;
    o[0]=(bf16_t)a.x; o[1]=(bf16_t)a.y; o[2]=(bf16_t)a.z; o[3]=(bf16_t)a.w;
    o[4]=(bf16_t)b.x; o[5]=(bf16_t)b.y; o[6]=(bf16_t)b.z; o[7]=(bf16_t)b.w;
    *(bf16x8*)(dst + (size_t)idx * 8) = o;
}

// ---------------------------------------------------------------------------
// 256x256-tile grouped GEMM, C = A * B^T per expert, K = 2048, BK = 64.
// 512 threads = 8 waves (2M x 4N), per-wave 128x64 output, acc[8][4] f32x4.
// 8-phase-per-2-K-tiles schedule collapsed to 4 quadrant-phases per K-tile:
//   q0: ds A(qm0)+B(qn0), stage A_h1(j+1)            -> MFMA quad(0,0)
//   q1: ds B(qn1)                                    -> MFMA quad(0,1)
//   q2: ds A(qm1),        stage B_h0(j+2)            -> MFMA quad(1,0)
//   q3:                   stage A_h0+B_h1(j+2), vmcnt(6) -> MFMA quad(1,1)
// Safety: each wave only ever reads A-half wm / B-half wn>>1; a region is
// overwritten only in phases after its last read was certified by the previous
// phase's barrier. Counted vmcnt(6) = 2 loads x 3 half-tiles in flight (T4).
// LDS reads XOR-swizzled byte^=((row&7)<<4); staging keeps linear LDS dest and
// pre-swizzles the GLOBAL source slot (rule #21).
// EPI==0: A rows gathered via inv (token rows), exact-GELU + bf16 store.
// EPI==1: A = hb rows direct, atomicAdd combine into Out[tok].
// ---------------------------------------------------------------------------
template <int EPI>
__global__ __launch_bounds__(512, 2)
void k_gemm(const bf16_t* __restrict__ A, const bf16_t* __restrict__ B,
            bf16_t* __restrict__ Hout, float* __restrict__ Out,
            const int* __restrict__ inv)
{
    // T1: 512 wgs, 8 XCDs -> 64 consecutive tiles per XCD (= one expert)
    int wg   = (blockIdx.x & 7) * 64 + (blockIdx.x >> 3);
    int e    = wg >> 6;
    int t    = wg & 63;                 // 8x8 tiles of 256^2 per expert
    int row0 = (t >> 3) * 256;
    int col0 = (t & 7) * 256;
    const bf16_t* Be = B + (size_t)e * 2048 * KD;

    __shared__ __align__(16) bf16_t lds[2 * 2 * 16384];   // [buf][A/B][256*64], 128 KiB

    int tid  = threadIdx.x;
    int lane = tid & 63;
    int wid  = tid >> 6;
    int wm   = wid >> 2;                // 0..1: A-half this wave reads
    int wn   = wid & 3;                 // 0..3: B-quarter (half = wn>>1)

    // ---- staging source pointers (global slot pre-swizzled; loop-invariant) ----
    int rr = tid >> 3;                          // row within 64-row (h,l) group
    int g8 = ((tid & 7) ^ (rr & 7)) * 8;        // swizzled 16B-slot, in elements
    const bf16_t* ap[2][2];
    const bf16_t* bp[2][2];
    #pragma unroll
    for (int h = 0; h < 2; h++)
        #pragma unroll
        for (int l = 0; l < 2; l++) {
            int ra = row0 + h * 128 + l * 64 + rr;
            if (EPI == 0) ap[h][l] = A + (size_t)(inv[e * CAP + ra] / TOPK) * KD + g8;
            else          ap[h][l] = A + ((size_t)e * CAP + ra) * KD + g8;
            bp[h][l] = Be + (size_t)(col0 + h * 128 + l * 64 + rr) * KD + g8;
        }

#define STG(m_, pp, h_, jt) do { \
        bf16_t* d_ = lds + (((jt) & 1) * 32768 + (m_) * 16384 + (h_) * 8192 + tid * 8); \
        async16(pp[h_][0] + (size_t)(jt) * 64, d_); \
        async16(pp[h_][1] + (size_t)(jt) * 64, d_ + 4096); \
    } while (0)

    // ---- compute-side fragment addressing (T2 swizzled read) ----
    int lm  = lane & 15;
    int lkq = lane >> 4;                        // 0..3
    int sw  = (lane & 7) << 4;                  // byte XOR, row&7 == lane&7
    int cA0 = ((lkq * 16) ^ sw) >> 1;           // elements, ks=0
    int cA1 = ((64 + lkq * 16) ^ sw) >> 1;      // elements, ks=1

    f32x4  acc[8][4] = {};
    bf16x8 af[4][2], bf2[2][2][2];

#define LOADA(qm) do { _Pragma("unroll") \
        for (int i = 0; i < 4; i++) { \
            const bf16_t* rp_ = Ab + (wm * 128 + (qm) * 64 + i * 16 + lm) * 64; \
            af[i][0] = *(const bf16x8*)(rp_ + cA0); \
            af[i][1] = *(const bf16x8*)(rp_ + cA1); } } while (0)

#define LOADB(qn) do { _Pragma("unroll") \
        for (int jj = 0; jj < 2; jj++) { \
            const bf16_t* rp_ = Bb + (wn * 64 + (qn) * 32 + jj * 16 + lm) * 64; \
            bf2[qn][jj][0] = *(const bf16x8*)(rp_ + cA0); \
            bf2[qn][jj][1] = *(const bf16x8*)(rp_ + cA1); } } while (0)

#define MFMAQ(qm, qn) do { \
        __builtin_amdgcn_s_setprio(1); \
        _Pragma("unroll") \
        for (int i = 0; i < 4; i++) \
            _Pragma("unroll") \
            for (int jj = 0; jj < 2; jj++) { \
                acc[(qm)*4+i][(qn)*2+jj] = __builtin_amdgcn_mfma_f32_16x16x32_bf16( \
                    af[i][0], bf2[qn][jj][0], acc[(qm)*4+i][(qn)*2+jj], 0, 0, 0); \
                acc[(qm)*4+i][(qn)*2+jj] = __builtin_amdgcn_mfma_f32_16x16x32_bf16( \
                    af[i][1], bf2[qn][jj][1], acc[(qm)*4+i][(qn)*2+jj], 0, 0, 0); \
            } \
        __builtin_amdgcn_s_setprio(0); \
    } while (0)

    // ---- prologue: tile0 full; tile1 {B_h0, A_h0, B_h1} (A_h1(1) comes at q0@0)
    STG(0, ap, 0, 0); STG(0, ap, 1, 0); STG(1, bp, 0, 0); STG(1, bp, 1, 0);
    STG(1, bp, 0, 1); STG(0, ap, 0, 1); STG(1, bp, 1, 1);
    asm volatile("s_waitcnt vmcnt(6)" ::: "memory");   // tile0's 8 loads retired
    BAR();

    for (int j = 0; j < NT; ++j) {
        const bf16_t* Ab = lds + (j & 1) * 32768;
        const bf16_t* Bb = Ab + 16384;
        // ---- q0
        LOADA(0); LOADB(0);
        if (j + 1 < NT) STG(0, ap, 1, j + 1);          // A_h1 -> other buffer
        BAR();
        MFMAQ(0, 0);
        BAR();
        // ---- q1
        LOADB(1);
        BAR();
        MFMAQ(0, 1);
        BAR();
        // ---- q2
        LOADA(1);
        if (j + 2 < NT) STG(1, bp, 0, j + 2);          // B_h0 reads certified @q1-end
        BAR();
        MFMAQ(1, 0);
        BAR();
        // ---- q3
        if (j + 2 < NT) {
            STG(0, ap, 0, j + 2); STG(1, bp, 1, j + 2);
            asm volatile("s_waitcnt vmcnt(6)" ::: "memory");  // tile j+1 resident
        } else if (j + 1 < NT) {
            asm volatile("s_waitcnt vmcnt(0)" ::: "memory");  // epilogue drain
        }
        BAR();
        MFMAQ(1, 1);
        BAR();
    }

    // ---- epilogue: C frag (row,col): row=(lane>>4)*4+reg (+A-frag base), col=lane&15
    int rbase = lkq * 4;
    if (EPI == 0) {
        #pragma unroll
        for (int mi = 0; mi < 8; mi++) {
            int row = row0 + wm * 128 + mi * 16 + rbase;
            #pragma unroll
            for (int nj = 0; nj < 4; nj++) {
                int col = col0 + wn * 64 + nj * 16 + lm;
                #pragma unroll
                for (int r = 0; r < 4; r++) {
                    float v = acc[mi][nj][r];
                    v = 0.5f * v * (1.0f + erff(v * 0.70710678118f));
                    Hout[((size_t)e * CAP + row + r) * FFN_ + col] = (bf16_t)v;
                }
            }
        }
    } else {
        #pragma unroll
        for (int mi = 0; mi < 8; mi++) {
            #pragma unroll
            for (int r = 0; r < 4; r++) {
                int gm  = e * CAP + row0 + wm * 128 + mi * 16 + rbase + r;
                int tok = inv[gm] / TOPK;
                #pragma unroll
                for (int nj = 0; nj < 4; nj++) {
                    int col = col0 + wn * 64 + nj * 16 + lm;
                    atomicAdd(&Out[(size_t)tok * HIDDEN + col], acc[mi][nj][r]);
                }
            }
        }
    }
#undef STG
#undef LOADA
#undef LOADB
#undef MFMAQ
}

extern "C" void kernel_launch(void* const* d_in, const int* in_sizes, int n_in,
                              void* d_out, int out_size, void* d_ws, size_t ws_size,
                              hipStream_t stream) {
    const float* x    = (const float*)d_in[0];
    const float* w1   = (const float*)d_in[1];
    const float* w2   = (const float*)d_in[2];
    const int*   scat = (const int*)d_in[3];
    float* out = (float*)d_out;

    char* ws = (char*)d_ws;
    size_t off = 0;
    int*    inv = (int*)(ws + off);     off += 65536;                          // MTOT*4, padded
    bf16_t* xbt = (bf16_t*)(ws + off);  off += (size_t)NTOK * HIDDEN * 2;      // 32 MB (L3-resident)
    bf16_t* w1b = (bf16_t*)(ws + off);  off += (size_t)NEXP * FFN_ * HIDDEN * 2;
    bf16_t* w2b = (bf16_t*)(ws + off);  off += (size_t)NEXP * HIDDEN * FFN_ * 2;
    bf16_t* hb  = (bf16_t*)(ws + off);  off += (size_t)MTOT * FFN_ * 2;

    hipMemsetAsync(d_out, 0, (size_t)out_size * sizeof(float), stream);

    k_build_inv<<<MTOT / 256, 256, 0, stream>>>(scat, inv);
    k_cast<<<NTOK * (HIDDEN / 8) / 256, 256, 0, stream>>>(x, xbt);   // cast x ONCE; GEMM1 gathers
    int nwb = NEXP * FFN_ * (HIDDEN / 8) / 256;                      // 16384 blocks
    k_cast<<<nwb, 256, 0, stream>>>(w1, w1b);
    k_cast<<<nwb, 256, 0, stream>>>(w2, w2b);

    k_gemm<0><<<NEXP * 64, 512, 0, stream>>>(xbt, w1b, hb, nullptr, inv);
    k_gemm<1><<<NEXP * 64, 512, 0, stream>>>(hb, w2b, nullptr, out, inv);
}

// Round 2
// 501.441 us; speedup vs baseline: 1.7250x; 1.3778x over previous
//
#include <hip/hip_runtime.h>
#include <hip/hip_bf16.h>
#include <math.h>

#define NTOK   8192
#define HIDDEN 2048
#define FFN_   2048
#define NEXP   8
#define TOPK   2
#define MTOT   (NTOK*TOPK)   // 16384 scattered rows
#define CAP    (MTOT/NEXP)   // 2048 rows per expert
#define KD     2048          // K of both GEMMs
#define NT     32            // K-tiles of 64

typedef __bf16 bf16_t;
typedef __attribute__((ext_vector_type(8))) __bf16 bf16x8;
typedef __attribute__((ext_vector_type(4))) float  f32x4;

__device__ __forceinline__ void async16(const bf16_t* g, bf16_t* l) {
    __builtin_amdgcn_global_load_lds(
        (const __attribute__((address_space(1))) void*)g,
        (__attribute__((address_space(3))) void*)l, 16, 0, 0);
}

#define FENCE() asm volatile("" ::: "memory")
#define BAR()   do { FENCE(); __builtin_amdgcn_s_barrier(); FENCE(); } while (0)

__global__ void k_build_inv(const int* __restrict__ scat, int* __restrict__ inv) {
    int i = blockIdx.x * 256 + threadIdx.x;
    inv[scat[i]] = i;
}

// pairing probe: token i's two copies must land in rows {2m, 2m+1}
__global__ void k_check(const int* __restrict__ scat, int* __restrict__ flag) {
    int i = blockIdx.x * 256 + threadIdx.x;          // [0, NTOK)
    if ((scat[2 * i] ^ scat[2 * i + 1]) != 1) atomicOr(flag, 1);
}

// fp32 -> bf16 cast, 8 elems/thread
__global__ void k_cast(const float* __restrict__ src, bf16_t* __restrict__ dst) {
    int idx = blockIdx.x * 256 + threadIdx.x;
    const float4* p = (const float4*)(src + (size_t)idx * 8);
    float4 a = p[0], b = p[1];
    bf16x8 o;
    o[0]=(bf16_t)a.x; o[1]=(bf16_t)a.y; o[2]=(bf16_t)a.z; o[3]=(bf16_t)a.w;
    o[4]=(bf16_t)b.x; o[5]=(bf16_t)b.y; o[6]=(bf16_t)b.z; o[7]=(bf16_t)b.w;
    *(bf16x8*)(dst + (size_t)idx * 8) = o;
}

// ---------------------------------------------------------------------------
// 256x256-tile grouped GEMM, C = A*B^T per expert, K=2048, BK=64, 8 waves.
// paired mode (flag==0): per expert only 1024 UNIQUE rows (token pairs merged)
//   -> 4 row-tiles/expert, 256 active blocks (1 round, 1/CU), EPI1 writes
//   Out[tok] = 2*acc as a plain store (exclusive ownership, no atomics).
// unpaired fallback: round-1 general path, 512 blocks, atomic combine.
// Schedule: 4 quadrant-phases/K-tile, counted vmcnt(6), T2 swizzle, T5 setprio.
// Staging placement: q0:A_h1(j+1)  q2:B_h0,B_h1(j+2)  q3:A_h0(j+2)+vmcnt(6).
// ---------------------------------------------------------------------------
template <int EPI>
__global__ __launch_bounds__(512, 2)
void k_gemm(const bf16_t* __restrict__ A, const bf16_t* __restrict__ B,
            bf16_t* __restrict__ Hout, float* __restrict__ Out,
            const int* __restrict__ inv, const int* __restrict__ flag)
{
    const int paired = (*flag == 0);
    const int per_e  = paired ? 32 : 64;         // tiles per expert
    int idx = blockIdx.x >> 3;
    int e   = blockIdx.x & 7;                    // T1: expert == XCD
    if (idx >= per_e) return;                    // early-exit half the grid (paired)
    int row0 = (idx >> 3) * 256;
    int col0 = (idx & 7) * 256;
    const int Mcap = paired ? 1024 : 2048;       // rows per expert in A/Hout space
    const bf16_t* Be = B + (size_t)e * 2048 * KD;

    __shared__ __align__(16) bf16_t lds[2 * 2 * 16384];   // 128 KiB

    int tid  = threadIdx.x;
    int lane = tid & 63;
    int wid  = tid >> 6;
    int wm   = wid >> 2;                // 0..1: A-half
    int wn   = wid & 3;                 // 0..3: B-quarter

    // ---- staging source pointers (global slot pre-swizzled; loop-invariant) ----
    int rr = tid >> 3;
    int g8 = ((tid & 7) ^ (rr & 7)) * 8;
    const bf16_t* ap[2][2];
    const bf16_t* bp[2][2];
    #pragma unroll
    for (int h = 0; h < 2; h++)
        #pragma unroll
        for (int l = 0; l < 2; l++) {
            int ra = row0 + h * 128 + l * 64 + rr;
            if (EPI == 0) {
                int sidx = paired ? 2 * (e * 1024 + ra) : (e * 2048 + ra);
                ap[h][l] = A + (size_t)(inv[sidx] / TOPK) * KD + g8;
            } else {
                ap[h][l] = A + ((size_t)e * Mcap + ra) * KD + g8;
            }
            bp[h][l] = Be + (size_t)(col0 + h * 128 + l * 64 + rr) * KD + g8;
        }

#define STG(m_, pp, h_, jt) do { \
        bf16_t* d_ = lds + (((jt) & 1) * 32768 + (m_) * 16384 + (h_) * 8192 + tid * 8); \
        async16(pp[h_][0] + (size_t)(jt) * 64, d_); \
        async16(pp[h_][1] + (size_t)(jt) * 64, d_ + 4096); \
    } while (0)

    // ---- compute-side fragment addressing (T2 swizzled read) ----
    int lm  = lane & 15;
    int lkq = lane >> 4;
    int sw  = (lane & 7) << 4;
    int cA0 = ((lkq * 16) ^ sw) >> 1;
    int cA1 = ((64 + lkq * 16) ^ sw) >> 1;

    f32x4  acc[8][4] = {};
    bf16x8 af[4][2], bf2[2][2][2];

#define LOADA(qm) do { _Pragma("unroll") \
        for (int i = 0; i < 4; i++) { \
            const bf16_t* rp_ = Ab + (wm * 128 + (qm) * 64 + i * 16 + lm) * 64; \
            af[i][0] = *(const bf16x8*)(rp_ + cA0); \
            af[i][1] = *(const bf16x8*)(rp_ + cA1); } } while (0)

#define LOADB(qn) do { _Pragma("unroll") \
        for (int jj = 0; jj < 2; jj++) { \
            const bf16_t* rp_ = Bb + (wn * 64 + (qn) * 32 + jj * 16 + lm) * 64; \
            bf2[qn][jj][0] = *(const bf16x8*)(rp_ + cA0); \
            bf2[qn][jj][1] = *(const bf16x8*)(rp_ + cA1); } } while (0)

#define MFMAQ(qm, qn) do { \
        __builtin_amdgcn_s_setprio(1); \
        _Pragma("unroll") \
        for (int i = 0; i < 4; i++) \
            _Pragma("unroll") \
            for (int jj = 0; jj < 2; jj++) { \
                acc[(qm)*4+i][(qn)*2+jj] = __builtin_amdgcn_mfma_f32_16x16x32_bf16( \
                    af[i][0], bf2[qn][jj][0], acc[(qm)*4+i][(qn)*2+jj], 0, 0, 0); \
                acc[(qm)*4+i][(qn)*2+jj] = __builtin_amdgcn_mfma_f32_16x16x32_bf16( \
                    af[i][1], bf2[qn][jj][1], acc[(qm)*4+i][(qn)*2+jj], 0, 0, 0); \
            } \
        __builtin_amdgcn_s_setprio(0); \
    } while (0)

    // ---- prologue: tile0 full; tile1 {A_h0, B_h0, B_h1} (A_h1(1) at q0@j=0)
    STG(0, ap, 0, 0); STG(0, ap, 1, 0); STG(1, bp, 0, 0); STG(1, bp, 1, 0);
    STG(0, ap, 0, 1); STG(1, bp, 0, 1); STG(1, bp, 1, 1);
    asm volatile("s_waitcnt vmcnt(6)" ::: "memory");   // tile0's 8 loads retired
    BAR();

    for (int j = 0; j < NT; ++j) {
        const bf16_t* Ab = lds + (j & 1) * 32768;
        const bf16_t* Bb = Ab + 16384;
        // ---- q0
        LOADA(0); LOADB(0);
        if (j + 1 < NT) STG(0, ap, 1, j + 1);
        BAR();
        MFMAQ(0, 0);
        BAR();
        // ---- q1
        LOADB(1);
        BAR();
        MFMAQ(0, 1);
        BAR();
        // ---- q2: B rows of current buf fully consumed by end of q1
        LOADA(1);
        if (j + 2 < NT) { STG(1, bp, 0, j + 2); STG(1, bp, 1, j + 2); }
        BAR();
        MFMAQ(1, 0);
        BAR();
        // ---- q3
        if (j + 2 < NT) {
            STG(0, ap, 0, j + 2);
            asm volatile("s_waitcnt vmcnt(6)" ::: "memory");  // tile j+1 resident
        } else if (j + 1 < NT) {
            asm volatile("s_waitcnt vmcnt(0)" ::: "memory");
        }
        BAR();
        MFMAQ(1, 1);
        BAR();
    }

    // ---- epilogue: frag (row,col): row = lkq*4 + reg (+frag base), col = lane&15
    int rbase = lkq * 4;
    if (EPI == 0) {
        #pragma unroll
        for (int mi = 0; mi < 8; mi++) {
            int row = row0 + wm * 128 + mi * 16 + rbase;
            #pragma unroll
            for (int nj = 0; nj < 4; nj++) {
                int col = col0 + wn * 64 + nj * 16 + lm;
                #pragma unroll
                for (int r = 0; r < 4; r++) {
                    float v = acc[mi][nj][r];
                    v = 0.5f * v * (1.0f + erff(v * 0.70710678118f));
                    Hout[((size_t)e * Mcap + row + r) * FFN_ + col] = (bf16_t)v;
                }
            }
        }
    } else if (paired) {
        // exclusive ownership: token's both copies merged -> plain store of 2*acc
        #pragma unroll
        for (int mi = 0; mi < 8; mi++) {
            #pragma unroll
            for (int r = 0; r < 4; r++) {
                int u   = e * 1024 + row0 + wm * 128 + mi * 16 + rbase + r;
                int tok = inv[2 * u] / TOPK;
                #pragma unroll
                for (int nj = 0; nj < 4; nj++) {
                    int col = col0 + wn * 64 + nj * 16 + lm;
                    Out[(size_t)tok * HIDDEN + col] = 2.0f * acc[mi][nj][r];
                }
            }
        }
    } else {
        #pragma unroll
        for (int mi = 0; mi < 8; mi++) {
            #pragma unroll
            for (int r = 0; r < 4; r++) {
                int gm  = e * 2048 + row0 + wm * 128 + mi * 16 + rbase + r;
                int tok = inv[gm] / TOPK;
                #pragma unroll
                for (int nj = 0; nj < 4; nj++) {
                    int col = col0 + wn * 64 + nj * 16 + lm;
                    atomicAdd(&Out[(size_t)tok * HIDDEN + col], acc[mi][nj][r]);
                }
            }
        }
    }
#undef STG
#undef LOADA
#undef LOADB
#undef MFMAQ
}

extern "C" void kernel_launch(void* const* d_in, const int* in_sizes, int n_in,
                              void* d_out, int out_size, void* d_ws, size_t ws_size,
                              hipStream_t stream) {
    const float* x    = (const float*)d_in[0];
    const float* w1   = (const float*)d_in[1];
    const float* w2   = (const float*)d_in[2];
    const int*   scat = (const int*)d_in[3];
    float* out = (float*)d_out;

    char* ws = (char*)d_ws;
    size_t off = 0;
    int*    inv   = (int*)(ws + off);   off += 65536;                          // MTOT*4
    int*    flagp = (int*)(ws + off);   off += 256;
    bf16_t* xbt = (bf16_t*)(ws + off);  off += (size_t)NTOK * HIDDEN * 2;      // 32 MB
    bf16_t* w1b = (bf16_t*)(ws + off);  off += (size_t)NEXP * FFN_ * HIDDEN * 2;
    bf16_t* w2b = (bf16_t*)(ws + off);  off += (size_t)NEXP * HIDDEN * FFN_ * 2;
    bf16_t* hb  = (bf16_t*)(ws + off);  off += (size_t)MTOT * FFN_ * 2;

    hipMemsetAsync(d_out, 0, (size_t)out_size * sizeof(float), stream);
    hipMemsetAsync(flagp, 0, 4, stream);

    k_build_inv<<<MTOT / 256, 256, 0, stream>>>(scat, inv);
    k_check<<<NTOK / 256, 256, 0, stream>>>(scat, flagp);
    k_cast<<<NTOK * (HIDDEN / 8) / 256, 256, 0, stream>>>(x, xbt);
    int nwb = NEXP * FFN_ * (HIDDEN / 8) / 256;
    k_cast<<<nwb, 256, 0, stream>>>(w1, w1b);
    k_cast<<<nwb, 256, 0, stream>>>(w2, w2b);

    k_gemm<0><<<NEXP * 64, 512, 0, stream>>>(xbt, w1b, hb, nullptr, inv, flagp);
    k_gemm<1><<<NEXP * 64, 512, 0, stream>>>(hb, w2b, nullptr, out, inv, flagp);
}

// Round 3
// 496.509 us; speedup vs baseline: 1.7421x; 1.0099x over previous
//
#include <hip/hip_runtime.h>
#include <hip/hip_bf16.h>
#include <math.h>

#define NTOK   8192
#define HIDDEN 2048
#define FFN_   2048
#define NEXP   8
#define TOPK   2
#define MTOT   (NTOK*TOPK)   // 16384 scattered rows
#define CAP    (MTOT/NEXP)   // 2048 rows per expert
#define KD     2048          // K of both GEMMs
#define NT     32            // K-tiles of 64

typedef __bf16 bf16_t;
typedef __attribute__((ext_vector_type(8))) __bf16 bf16x8;
typedef __attribute__((ext_vector_type(4))) float  f32x4;

__device__ __forceinline__ void async16(const bf16_t* g, bf16_t* l) {
    __builtin_amdgcn_global_load_lds(
        (const __attribute__((address_space(1))) void*)g,
        (__attribute__((address_space(3))) void*)l, 16, 0, 0);
}

#define FENCE() asm volatile("" ::: "memory")
#define BAR()   do { FENCE(); __builtin_amdgcn_s_barrier(); FENCE(); } while (0)

// inv build + pairing probe in one dispatch
__global__ void k_prep(const int* __restrict__ scat, int* __restrict__ inv,
                       int* __restrict__ flag) {
    int i = blockIdx.x * 256 + threadIdx.x;          // [0, MTOT)
    inv[scat[i]] = i;
    if (i < NTOK && ((scat[2 * i] ^ scat[2 * i + 1]) != 1)) atomicOr(flag, 1);
}

// all three fp32->bf16 casts in one dispatch; 2048 elems per block
__global__ void k_cast_all(const float* __restrict__ x,  const float* __restrict__ w1,
                           const float* __restrict__ w2, bf16_t* __restrict__ xb,
                           bf16_t* __restrict__ w1b, bf16_t* __restrict__ w2b) {
    int b = blockIdx.x;
    const float* s; bf16_t* d; size_t base;
    if (b < 8192)       { s = x;  d = xb;  base = (size_t)b * 2048; }
    else if (b < 24576) { s = w1; d = w1b; base = (size_t)(b - 8192) * 2048; }
    else                { s = w2; d = w2b; base = (size_t)(b - 24576) * 2048; }
    size_t i = base + (size_t)threadIdx.x * 8;
    const float4* p = (const float4*)(s + i);
    float4 a = p[0], c = p[1];
    bf16x8 o;
    o[0]=(bf16_t)a.x; o[1]=(bf16_t)a.y; o[2]=(bf16_t)a.z; o[3]=(bf16_t)a.w;
    o[4]=(bf16_t)c.x; o[5]=(bf16_t)c.y; o[6]=(bf16_t)c.z; o[7]=(bf16_t)c.w;
    *(bf16x8*)(d + i) = o;
}

// ---------------------------------------------------------------------------
// 256x256-tile grouped GEMM, C = A*B^T per expert, K=2048, BK=64, 8 waves.
// paired mode (flag==0): 1024 unique rows/expert, 256 blocks, EPI1 plain-store.
// Phase schedule (4 quadrant-phases/K-tile), ds_reads balanced {8,4,8,4}:
//   q0: LOADA(0)[8]          stage A_h1(j+1)          -> M(0,0) af x bfn
//   q1: LOADB1  [4]                                   -> M(0,1) af x bf1
//   q2: LOADA(1)[8]          stage B_h0,B_h1(j+2)     -> M(1,0) af x bfn
//   q3: LOADB0N [4] (next)   stage A_h0(j+2), vmcnt(6)-> M(1,1) af x bf1
// bfn (B quadrant 0) is prefetched one phase ahead from the NEXT LDS buffer,
// right after the vmcnt(6)+BAR that certifies that buffer's residency.
// Counted vmcnt(6) = 3 half-tiles in flight; never drains in main loop (T4).
// T2 swizzle (linear LDS dest + pre-swizzled global src + swizzled ds_read).
// ---------------------------------------------------------------------------
template <int EPI>
__global__ __launch_bounds__(512, 2)
void k_gemm(const bf16_t* __restrict__ A, const bf16_t* __restrict__ B,
            bf16_t* __restrict__ Hout, float* __restrict__ Out,
            const int* __restrict__ inv, const int* __restrict__ flag)
{
    const int paired = (*flag == 0);
    const int per_e  = paired ? 32 : 64;
    int idx = blockIdx.x >> 3;
    int e   = blockIdx.x & 7;                    // T1: expert == XCD
    if (idx >= per_e) return;
    int row0 = (idx >> 3) * 256;
    int col0 = (idx & 7) * 256;
    const int Mcap = paired ? 1024 : 2048;
    const bf16_t* Be = B + (size_t)e * 2048 * KD;

    __shared__ __align__(16) bf16_t lds[2 * 2 * 16384];   // 128 KiB

    int tid  = threadIdx.x;
    int lane = tid & 63;
    int wid  = tid >> 6;
    int wm   = wid >> 2;                // 0..1: A-half
    int wn   = wid & 3;                 // 0..3: B-quarter

    // ---- staging source pointers (global slot pre-swizzled; loop-invariant) ----
    int rr = tid >> 3;
    int g8 = ((tid & 7) ^ (rr & 7)) * 8;
    const bf16_t* ap[2][2];
    const bf16_t* bp[2][2];
    #pragma unroll
    for (int h = 0; h < 2; h++)
        #pragma unroll
        for (int l = 0; l < 2; l++) {
            int ra = row0 + h * 128 + l * 64 + rr;
            if (EPI == 0) {
                int sidx = paired ? 2 * (e * 1024 + ra) : (e * 2048 + ra);
                ap[h][l] = A + (size_t)(inv[sidx] / TOPK) * KD + g8;
            } else {
                ap[h][l] = A + ((size_t)e * Mcap + ra) * KD + g8;
            }
            bp[h][l] = Be + (size_t)(col0 + h * 128 + l * 64 + rr) * KD + g8;
        }

#define STG(m_, pp, h_, jt) do { \
        bf16_t* d_ = lds + (((jt) & 1) * 32768 + (m_) * 16384 + (h_) * 8192 + tid * 8); \
        async16(pp[h_][0] + (size_t)(jt) * 64, d_); \
        async16(pp[h_][1] + (size_t)(jt) * 64, d_ + 4096); \
    } while (0)

    // ---- compute-side fragment addressing (T2 swizzled read) ----
    int lm  = lane & 15;
    int lkq = lane >> 4;
    int sw  = (lane & 7) << 4;
    int cA0 = ((lkq * 16) ^ sw) >> 1;
    int cA1 = ((64 + lkq * 16) ^ sw) >> 1;

    f32x4  acc[8][4] = {};
    bf16x8 af[4][2];          // A quadrant (reloaded q0/q2)
    bf16x8 bfn[2][2];         // B quadrant 0 (prefetched at q3 from next buffer)
    bf16x8 bf1[2][2];         // B quadrant 1 (loaded in-phase at q1)

#define LOADA(qm) do { _Pragma("unroll") \
        for (int i = 0; i < 4; i++) { \
            const bf16_t* rp_ = Ab + (wm * 128 + (qm) * 64 + i * 16 + lm) * 64; \
            af[i][0] = *(const bf16x8*)(rp_ + cA0); \
            af[i][1] = *(const bf16x8*)(rp_ + cA1); } } while (0)

#define LOADB1() do { _Pragma("unroll") \
        for (int jj = 0; jj < 2; jj++) { \
            const bf16_t* rp_ = Bb + (wn * 64 + 32 + jj * 16 + lm) * 64; \
            bf1[jj][0] = *(const bf16x8*)(rp_ + cA0); \
            bf1[jj][1] = *(const bf16x8*)(rp_ + cA1); } } while (0)

#define LOADB0N(Bsrc) do { _Pragma("unroll") \
        for (int jj = 0; jj < 2; jj++) { \
            const bf16_t* rp_ = (Bsrc) + (wn * 64 + jj * 16 + lm) * 64; \
            bfn[jj][0] = *(const bf16x8*)(rp_ + cA0); \
            bfn[jj][1] = *(const bf16x8*)(rp_ + cA1); } } while (0)

#define MFMAQ(qm, BARR) do { \
        __builtin_amdgcn_s_setprio(1); \
        _Pragma("unroll") \
        for (int i = 0; i < 4; i++) \
            _Pragma("unroll") \
            for (int jj = 0; jj < 2; jj++) { \
                acc[(qm)*4+i][(BQ)*2+jj] = __builtin_amdgcn_mfma_f32_16x16x32_bf16( \
                    af[i][0], BARR[jj][0], acc[(qm)*4+i][(BQ)*2+jj], 0, 0, 0); \
                acc[(qm)*4+i][(BQ)*2+jj] = __builtin_amdgcn_mfma_f32_16x16x32_bf16( \
                    af[i][1], BARR[jj][1], acc[(qm)*4+i][(BQ)*2+jj], 0, 0, 0); \
            } \
        __builtin_amdgcn_s_setprio(0); \
    } while (0)

    // ---- prologue: tile0 full (8 loads); tile1 {A_h0, B_h0, B_h1} (6 loads)
    STG(0, ap, 0, 0); STG(0, ap, 1, 0); STG(1, bp, 0, 0); STG(1, bp, 1, 0);
    STG(0, ap, 0, 1); STG(1, bp, 0, 1); STG(1, bp, 1, 1);
    asm volatile("s_waitcnt vmcnt(6)" ::: "memory");   // tile0's 8 loads retired
    BAR();
    {   // prefetch B0 of tile 0
        const bf16_t* Bb0 = lds + 16384;
        LOADB0N(Bb0);
    }

    for (int j = 0; j < NT; ++j) {
        const bf16_t* Ab = lds + (j & 1) * 32768;
        const bf16_t* Bb = Ab + 16384;
        // ---- q0: M(0,0) = A0 x B0(bfn)
        LOADA(0);
        if (j + 1 < NT) STG(0, ap, 1, j + 1);
        BAR();
        { enum { BQ = 0 }; MFMAQ(0, bfn); }
        BAR();
        // ---- q1: M(0,1) = A0 x B1
        LOADB1();
        BAR();
        { enum { BQ = 1 }; MFMAQ(0, bf1); }
        BAR();
        // ---- q2: M(1,0) = A1 x B0(bfn); B rows of current buf consumed @q1-end
        LOADA(1);
        if (j + 2 < NT) { STG(1, bp, 0, j + 2); STG(1, bp, 1, j + 2); }
        BAR();
        { enum { BQ = 0 }; MFMAQ(1, bfn); }
        BAR();
        // ---- q3: M(1,1) = A1 x B1; prefetch next tile's B0 after residency cert
        if (j + 2 < NT) {
            STG(0, ap, 0, j + 2);
            asm volatile("s_waitcnt vmcnt(6)" ::: "memory");  // tile j+1 resident
        } else if (j + 1 < NT) {
            asm volatile("s_waitcnt vmcnt(0)" ::: "memory");
        }
        BAR();
        if (j + 1 < NT) {
            const bf16_t* Bbn = lds + (((j + 1) & 1) * 32768) + 16384;
            LOADB0N(Bbn);
        }
        { enum { BQ = 1 }; MFMAQ(1, bf1); }
        BAR();
    }

    // ---- epilogue: frag (row,col): row = lkq*4 + reg (+frag base), col = lane&15
    int rbase = lkq * 4;
    if (EPI == 0) {
        #pragma unroll
        for (int mi = 0; mi < 8; mi++) {
            int row = row0 + wm * 128 + mi * 16 + rbase;
            #pragma unroll
            for (int nj = 0; nj < 4; nj++) {
                int col = col0 + wn * 64 + nj * 16 + lm;
                #pragma unroll
                for (int r = 0; r < 4; r++) {
                    float v = acc[mi][nj][r];
                    v = 0.5f * v * (1.0f + erff(v * 0.70710678118f));
                    Hout[((size_t)e * Mcap + row + r) * FFN_ + col] = (bf16_t)v;
                }
            }
        }
    } else if (paired) {
        #pragma unroll
        for (int mi = 0; mi < 8; mi++) {
            #pragma unroll
            for (int r = 0; r < 4; r++) {
                int u   = e * 1024 + row0 + wm * 128 + mi * 16 + rbase + r;
                int tok = inv[2 * u] / TOPK;
                #pragma unroll
                for (int nj = 0; nj < 4; nj++) {
                    int col = col0 + wn * 64 + nj * 16 + lm;
                    Out[(size_t)tok * HIDDEN + col] = 2.0f * acc[mi][nj][r];
                }
            }
        }
    } else {
        #pragma unroll
        for (int mi = 0; mi < 8; mi++) {
            #pragma unroll
            for (int r = 0; r < 4; r++) {
                int gm  = e * 2048 + row0 + wm * 128 + mi * 16 + rbase + r;
                int tok = inv[gm] / TOPK;
                #pragma unroll
                for (int nj = 0; nj < 4; nj++) {
                    int col = col0 + wn * 64 + nj * 16 + lm;
                    atomicAdd(&Out[(size_t)tok * HIDDEN + col], acc[mi][nj][r]);
                }
            }
        }
    }
#undef STG
#undef LOADA
#undef LOADB1
#undef LOADB0N
#undef MFMAQ
}

extern "C" void kernel_launch(void* const* d_in, const int* in_sizes, int n_in,
                              void* d_out, int out_size, void* d_ws, size_t ws_size,
                              hipStream_t stream) {
    const float* x    = (const float*)d_in[0];
    const float* w1   = (const float*)d_in[1];
    const float* w2   = (const float*)d_in[2];
    const int*   scat = (const int*)d_in[3];
    float* out = (float*)d_out;

    char* ws = (char*)d_ws;
    size_t off = 0;
    int*    inv   = (int*)(ws + off);   off += 65536;                          // MTOT*4
    int*    flagp = (int*)(ws + off);   off += 256;
    bf16_t* xbt = (bf16_t*)(ws + off);  off += (size_t)NTOK * HIDDEN * 2;      // 32 MB
    bf16_t* w1b = (bf16_t*)(ws + off);  off += (size_t)NEXP * FFN_ * HIDDEN * 2;
    bf16_t* w2b = (bf16_t*)(ws + off);  off += (size_t)NEXP * HIDDEN * FFN_ * 2;
    bf16_t* hb  = (bf16_t*)(ws + off);  off += (size_t)MTOT * FFN_ * 2;

    hipMemsetAsync(d_out, 0, (size_t)out_size * sizeof(float), stream);
    hipMemsetAsync(flagp, 0, 4, stream);

    k_prep<<<MTOT / 256, 256, 0, stream>>>(scat, inv, flagp);
    k_cast_all<<<8192 + 2 * 16384, 256, 0, stream>>>(x, w1, w2, xbt, w1b, w2b);

    k_gemm<0><<<NEXP * 64, 512, 0, stream>>>(xbt, w1b, hb, nullptr, inv, flagp);
    k_gemm<1><<<NEXP * 64, 512, 0, stream>>>(hb, w2b, nullptr, out, inv, flagp);
}